// Round 11
// baseline (95.835 us; speedup 1.0000x reference)
//
#include <hip/hip_runtime.h>
#include <math.h>

// DynamicRouting: C=1024, K=64, H=512.
// Round-11: round-9 structure with TWO fixes:
//  (1) slab second dim was [4] but indexed 0..7 (i2*2+ks) -> OOB clobbered
//      chatL/bvec (round-10 absmax 0.278). Now slab[2][8][64][8].
//  (2) __launch_bounds__(512,8) demanded 64 VGPR (acc alone = 64) -> spills.
//      Now (512,4) = 128-VGPR cap -> ~110 used, 2 blocks/CU co-resident.
// Wave layout (verified rounds 7-8): acc[i*4+j][r] = xh[k][g],
//   k = i*16 + (lane>>4)*4 + r, g = wave*64 + j*16 + (lane&15).
// A-frag reads are wave-contiguous 1024 B ds_read_b128 (no read conflicts).

#define KC 64
#define HD 512
#define NT 512

typedef _Float16 half8  __attribute__((ext_vector_type(8)));
typedef _Float16 half4v __attribute__((ext_vector_type(4)));
typedef float    f32x4  __attribute__((ext_vector_type(4)));

// ---------------- W -> fp16 ----------------
__launch_bounds__(256)
__global__ void cast_w_kernel(const float* __restrict__ W, _Float16* __restrict__ W16) {
    int i = blockIdx.x * 256 + threadIdx.x;       // 65536 float4 total
    float4 v = reinterpret_cast<const float4*>(W)[i];
    half4v h = { (_Float16)v.x, (_Float16)v.y, (_Float16)v.z, (_Float16)v.w };
    reinterpret_cast<half4v*>(W16)[i] = h;
}

// ---------------- fused proj + routing, 1 capsule per block ----------------
__launch_bounds__(NT, 4)   // 128-VGPR cap -> no spills, 2 blocks/CU
__global__ void routing_kernel(const float* __restrict__ enc,
                               const _Float16* __restrict__ W16,
                               float* __restrict__ out) {
    // fragment-order slab: [buf][i2*2+ks][l4*16+l15][e]  (i2 = k>>4, ks = h32-half)
    __shared__ _Float16 slab[2][8][64][8];      // 16 KB (dbuf)
    __shared__ float chatL[HD];                 // 2 KB
    __shared__ float bvec[KC];
    __shared__ float dvec[KC];
    __shared__ float bpart[8][KC];              // 2 KB per-wave b partials
    __shared__ float red[8];
    __shared__ float s_alpha;

    const int tid  = threadIdx.x;
    const int lane = tid & 63;
    const int wave = tid >> 6;                  // 0..7 (g-slice owner)
    const int l15  = lane & 15, l4 = lane >> 4;
    const int c    = blockIdx.x;
    const float* ebase = enc + (size_t)c * (KC * HD);

    if (tid < KC) bvec[tid] = 0.0f;

    f32x4 acc[16];
    #pragma unroll
    for (int i = 0; i < 16; ++i) acc[i] = (f32x4){0.f, 0.f, 0.f, 0.f};

    // ---- stage enc h-slab hs (64k x 64h fp32 -> fp16), fragment-order LDS ----
    auto stage = [&](int hs, int b) {
        #pragma unroll
        for (int j = 0; j < 2; ++j) {
            int idx = tid + (j << 9);              // 0..1023 float4s
            int r   = idx >> 4;                    // k row 0..63
            int c4  = (idx & 15) << 2;             // col offset in 64-col slab
            float4 v = *reinterpret_cast<const float4*>(ebase + (size_t)r * HD + hs * 64 + c4);
            half4v h = { (_Float16)v.x, (_Float16)v.y, (_Float16)v.z, (_Float16)v.w };
            int i2  = r >> 4;
            int ks  = c4 >> 5;
            int l4g = (c4 >> 3) & 3;
            int e0  = c4 & 7;                      // 0 or 4
            *reinterpret_cast<half4v*>(&slab[b][i2 * 2 + ks][l4g * 16 + (r & 15)][e0]) = h;
        }
    };

    const _Float16* wb = W16 + (size_t)(wave * 64 + l15) * HD + l4 * 8;

    // ---- projection: acc = Enc_c @ W^T, fp16 MFMA 16x16x32 ----
    stage(0, 0);
    for (int hs = 0; hs < 8; ++hs) {
        __syncthreads();
        if (hs < 7) stage(hs + 1, (hs + 1) & 1);
        const int b = hs & 1;
        #pragma unroll
        for (int ks = 0; ks < 2; ++ks) {
            half8 bf[4], af[4];
            #pragma unroll
            for (int j = 0; j < 4; ++j)
                bf[j] = *reinterpret_cast<const half8*>(wb + j * (16 * HD) + hs * 64 + ks * 32);
            #pragma unroll
            for (int i = 0; i < 4; ++i)
                af[i] = *reinterpret_cast<const half8*>(&slab[b][i * 2 + ks][lane][0]);
            #pragma unroll
            for (int i = 0; i < 4; ++i)
                #pragma unroll
                for (int j = 0; j < 4; ++j)
                    acc[i * 4 + j] = __builtin_amdgcn_mfma_f32_16x16x32_f16(af[i], bf[j], acc[i * 4 + j], 0, 0, 0);
        }
    }
    __syncthreads();

    // ---- routing: 3 iterations, x_hat register-resident ----
    for (int it = 0; it < 3; ++it) {
        if (it > 0) {
            if (wave == 0) {                    // softmax over K=64
                float v = bvec[lane];
                float m = v;
                #pragma unroll
                for (int off = 32; off; off >>= 1) m = fmaxf(m, __shfl_xor(m, off));
                float e = expf(v - m);
                float s = e;
                #pragma unroll
                for (int off = 32; off; off >>= 1) s += __shfl_xor(s, off);
                dvec[lane] = e / s;
            }
            __syncthreads();
        }

        // chat[g], g = wave*64 + j*16 + l15, in registers
        float chv[4];
        #pragma unroll
        for (int j = 0; j < 4; ++j) chv[j] = 0.f;
        #pragma unroll
        for (int i = 0; i < 4; ++i)
            #pragma unroll
            for (int r = 0; r < 4; ++r) {
                float dk = (it == 0) ? (1.0f / 64.0f) : dvec[i * 16 + l4 * 4 + r];
                #pragma unroll
                for (int j = 0; j < 4; ++j)
                    chv[j] += dk * acc[i * 4 + j][r];
            }
        #pragma unroll
        for (int j = 0; j < 4; ++j) {           // l4-reduce (4 k-chunks)
            chv[j] += __shfl_xor(chv[j], 16);
            chv[j] += __shfl_xor(chv[j], 32);
        }
        if (l4 == 0) {
            #pragma unroll
            for (int j = 0; j < 4; ++j)
                chatL[wave * 64 + j * 16 + l15] = chv[j];
        }
        {
            float p = chv[0] * chv[0] + chv[1] * chv[1] + chv[2] * chv[2] + chv[3] * chv[3];
            #pragma unroll
            for (int off = 1; off <= 8; off <<= 1) p += __shfl_xor(p, off);  // l15-reduce
            if (lane == 0) red[wave] = p;
        }
        __syncthreads();
        if (tid == 0) {
            float n2 = red[0] + red[1] + red[2] + red[3] + red[4] + red[5] + red[6] + red[7];
            s_alpha = sqrtf(n2) / (1.0f + n2);
        }
        __syncthreads();

        if (it < 2) {
            // b_k += alpha * sum_g xh[k][g] chat[g]
            #pragma unroll
            for (int i = 0; i < 4; ++i)
                #pragma unroll
                for (int r = 0; r < 4; ++r) {
                    float s = acc[i * 4 + 0][r] * chv[0]
                            + acc[i * 4 + 1][r] * chv[1]
                            + acc[i * 4 + 2][r] * chv[2]
                            + acc[i * 4 + 3][r] * chv[3];
                    #pragma unroll
                    for (int off = 1; off <= 8; off <<= 1) s += __shfl_xor(s, off);  // l15-reduce
                    if (l15 == 0) bpart[wave][i * 16 + l4 * 4 + r] = s;
                }
            __syncthreads();
            if (tid < KC) {
                float t = 0.f;
                #pragma unroll
                for (int w = 0; w < 8; ++w) t += bpart[w][tid];
                bvec[tid] += s_alpha * t;
            }
            __syncthreads();
        } else {
            out[(size_t)c * HD + tid] = s_alpha * chatL[tid];
        }
    }
}

extern "C" void kernel_launch(void* const* d_in, const int* in_sizes, int n_in,
                              void* d_out, int out_size, void* d_ws, size_t ws_size,
                              hipStream_t stream) {
    const float* enc = (const float*)d_in[0];   // [1024, 64, 512] fp32
    const float* W   = (const float*)d_in[1];   // [512, 512] fp32
    float* out       = (float*)d_out;           // [1024, 512] fp32
    _Float16* W16    = (_Float16*)d_ws;         // 512 KB
    (void)in_sizes; (void)n_in; (void)ws_size; (void)out_size;

    cast_w_kernel<<<256, 256, 0, stream>>>(W, W16);
    routing_kernel<<<1024, NT, 0, stream>>>(enc, W16, out);
}

// Round 12
// 81.148 us; speedup vs baseline: 1.1810x; 1.1810x over previous
//
#include <hip/hip_runtime.h>
#include <math.h>

// DynamicRouting: C=1024, K=64, H=512.
// Round-12: round-11 math (verified) + three latency fixes:
//  (a) T14 async-STAGE: enc loads for hs+1 issued at TOP of iter hs (regs),
//      cvt+ds_write at END -> ~600cy L3 latency hides under MFMA phase.
//      (round 8/11 invariance to occupancy => per-block serial stalls.)
//  (b) W16 pre-permuted to B-fragment order (cast kernel): bf load is a
//      coalesced lane*16B 1-KB dwordx4 (was 16-line gather), double-buffered
//      in regs one hs ahead -> fully hidden.
//  (c) slab write XOR-swizzle prow = row ^ (l4g<<1) (involution, both sides)
//      -> kills 4-way write conflicts; reads stay a full-coverage permutation.
// Wave layout (verified r7-r11): acc[i*4+j][r] = xh[k][g],
//   k = i*16 + (lane>>4)*4 + r, g = wave*64 + j*16 + (lane&15).

#define KC 64
#define HD 512
#define NT 512

typedef _Float16 half8  __attribute__((ext_vector_type(8)));
typedef _Float16 half4v __attribute__((ext_vector_type(4)));
typedef float    f32x4  __attribute__((ext_vector_type(4)));

// ---- W (fp32 row-major [g][h]) -> fp16 in B-fragment order ----
// flat u = (((wv*8 + hs)*2 + ks)*4 + j)*64 + lane ; element e in [0,8)
// maps to W[g][h], g = wv*64 + j*16 + (lane&15), h = hs*64+ks*32+(lane>>4)*8+e
__launch_bounds__(256)
__global__ void cast_w_kernel(const float* __restrict__ W, _Float16* __restrict__ Wp) {
    int u    = blockIdx.x * 256 + threadIdx.x;    // 0..32767
    int lane = u & 63;
    int j    = (u >> 6) & 3;
    int ks   = (u >> 8) & 1;
    int hs   = (u >> 9) & 7;
    int wv   = (u >> 12) & 7;
    int g  = wv * 64 + j * 16 + (lane & 15);
    int h0 = hs * 64 + ks * 32 + (lane >> 4) * 8;
    const float4* src = reinterpret_cast<const float4*>(W + (size_t)g * HD + h0);
    float4 a = src[0], b = src[1];
    half8 h = { (_Float16)a.x, (_Float16)a.y, (_Float16)a.z, (_Float16)a.w,
                (_Float16)b.x, (_Float16)b.y, (_Float16)b.z, (_Float16)b.w };
    *reinterpret_cast<half8*>(Wp + (size_t)u * 8) = h;
}

// ---- fused proj + routing, one capsule per block ----
__launch_bounds__(NT, 2)   // ~180 unified VGPR (incl 64 AGPR acc) -> no spills
__global__ void routing_kernel(const float* __restrict__ enc,
                               const _Float16* __restrict__ Wp,
                               float* __restrict__ out) {
    __shared__ _Float16 slab[2][8][64][8];      // 16 KB dbuf, fragment order
    __shared__ float chatL[HD];
    __shared__ float bvec[KC];
    __shared__ float dvec[KC];
    __shared__ float bpart[8][KC];
    __shared__ float red[8];
    __shared__ float s_alpha;

    const int tid  = threadIdx.x;
    const int lane = tid & 63;
    const int wave = tid >> 6;
    const int l15  = lane & 15, l4 = lane >> 4;
    const int c    = blockIdx.x;
    const float* ebase = enc + (size_t)c * (KC * HD);
    const _Float16* wbase = Wp + ((size_t)wave << 15) + (lane << 3);  // wave*32768 + lane*8

    if (tid < KC) bvec[tid] = 0.0f;

    f32x4 acc[16];
    #pragma unroll
    for (int i = 0; i < 16; ++i) acc[i] = (f32x4){0.f, 0.f, 0.f, 0.f};

    // staging geometry (j=0 row r0, j=1 row r0+32; same col group)
    const int r0   = tid >> 4;                  // 0..31
    const int c40  = (tid & 15) << 2;           // 0..60
    const int ks_w = c40 >> 5;
    const int l4g  = (c40 >> 3) & 3;
    const int e0w  = c40 & 7;                   // 0 or 4
    const int prow = (l4g * 16 + (r0 & 15)) ^ (l4g << 1);
    const int p0   = (r0 >> 4) * 2 + ks_w;      // plane for j=0 (0..3)
    const int p1   = p0 + 4;                    // plane for j=1
    const int plane_r = lane ^ ((lane >> 4) << 1);  // read-side involution

    float4 ev0, ev1;
    auto eload = [&](int hs) {
        ev0 = *reinterpret_cast<const float4*>(ebase + (size_t)r0 * HD + hs * 64 + c40);
        ev1 = *reinterpret_cast<const float4*>(ebase + (size_t)(r0 + 32) * HD + hs * 64 + c40);
    };
    auto ewrite = [&](int b) {
        half4v h0 = { (_Float16)ev0.x, (_Float16)ev0.y, (_Float16)ev0.z, (_Float16)ev0.w };
        half4v h1 = { (_Float16)ev1.x, (_Float16)ev1.y, (_Float16)ev1.z, (_Float16)ev1.w };
        *reinterpret_cast<half4v*>(&slab[b][p0][prow][e0w]) = h0;
        *reinterpret_cast<half4v*>(&slab[b][p1][prow][e0w]) = h1;
    };

    half8 bf[2][8];
    auto bload = [&](int hs) {
        #pragma unroll
        for (int q = 0; q < 8; ++q)
            bf[hs & 1][q] = *reinterpret_cast<const half8*>(wbase + hs * 4096 + q * 512);
    };

    // prologue: slab 0 + bf 0
    bload(0);
    eload(0);
    ewrite(0);

    #pragma unroll
    for (int hs = 0; hs < 8; ++hs) {
        __syncthreads();                          // slab[hs&1] ready for all waves
        if (hs < 7) { eload(hs + 1); bload(hs + 1); }   // issue-early (T14)
        #pragma unroll
        for (int ks = 0; ks < 2; ++ks) {
            half8 af[4];
            #pragma unroll
            for (int i = 0; i < 4; ++i)
                af[i] = *reinterpret_cast<const half8*>(&slab[hs & 1][i * 2 + ks][plane_r][0]);
            #pragma unroll
            for (int i = 0; i < 4; ++i)
                #pragma unroll
                for (int j = 0; j < 4; ++j)
                    acc[i * 4 + j] = __builtin_amdgcn_mfma_f32_16x16x32_f16(
                        af[i], bf[hs & 1][ks * 4 + j], acc[i * 4 + j], 0, 0, 0);
        }
        if (hs < 7) ewrite((hs + 1) & 1);         // write-late (T14)
    }
    __syncthreads();

    // ---- routing: 3 iterations, x_hat register-resident (verified r8/r11) ----
    for (int it = 0; it < 3; ++it) {
        if (it > 0) {
            if (wave == 0) {                    // softmax over K=64
                float v = bvec[lane];
                float m = v;
                #pragma unroll
                for (int off = 32; off; off >>= 1) m = fmaxf(m, __shfl_xor(m, off));
                float e = expf(v - m);
                float s = e;
                #pragma unroll
                for (int off = 32; off; off >>= 1) s += __shfl_xor(s, off);
                dvec[lane] = e / s;
            }
            __syncthreads();
        }

        // chat[g], g = wave*64 + j*16 + l15, in registers
        float chv[4];
        #pragma unroll
        for (int j = 0; j < 4; ++j) chv[j] = 0.f;
        #pragma unroll
        for (int i = 0; i < 4; ++i)
            #pragma unroll
            for (int r = 0; r < 4; ++r) {
                float dk = (it == 0) ? (1.0f / 64.0f) : dvec[i * 16 + l4 * 4 + r];
                #pragma unroll
                for (int j = 0; j < 4; ++j)
                    chv[j] += dk * acc[i * 4 + j][r];
            }
        #pragma unroll
        for (int j = 0; j < 4; ++j) {           // l4-reduce (4 k-chunks)
            chv[j] += __shfl_xor(chv[j], 16);
            chv[j] += __shfl_xor(chv[j], 32);
        }
        if (l4 == 0) {
            #pragma unroll
            for (int j = 0; j < 4; ++j)
                chatL[wave * 64 + j * 16 + l15] = chv[j];
        }
        {
            float p = chv[0] * chv[0] + chv[1] * chv[1] + chv[2] * chv[2] + chv[3] * chv[3];
            #pragma unroll
            for (int off = 1; off <= 8; off <<= 1) p += __shfl_xor(p, off);  // l15-reduce
            if (lane == 0) red[wave] = p;
        }
        __syncthreads();
        if (tid == 0) {
            float n2 = red[0] + red[1] + red[2] + red[3] + red[4] + red[5] + red[6] + red[7];
            s_alpha = sqrtf(n2) / (1.0f + n2);
        }
        __syncthreads();

        if (it < 2) {
            // b_k += alpha * sum_g xh[k][g] chat[g]
            #pragma unroll
            for (int i = 0; i < 4; ++i)
                #pragma unroll
                for (int r = 0; r < 4; ++r) {
                    float s = acc[i * 4 + 0][r] * chv[0]
                            + acc[i * 4 + 1][r] * chv[1]
                            + acc[i * 4 + 2][r] * chv[2]
                            + acc[i * 4 + 3][r] * chv[3];
                    #pragma unroll
                    for (int off = 1; off <= 8; off <<= 1) s += __shfl_xor(s, off);  // l15-reduce
                    if (l15 == 0) bpart[wave][i * 16 + l4 * 4 + r] = s;
                }
            __syncthreads();
            if (tid < KC) {
                float t = 0.f;
                #pragma unroll
                for (int w = 0; w < 8; ++w) t += bpart[w][tid];
                bvec[tid] += s_alpha * t;
            }
            __syncthreads();
        } else {
            out[(size_t)c * HD + tid] = s_alpha * chatL[tid];
        }
    }
}

extern "C" void kernel_launch(void* const* d_in, const int* in_sizes, int n_in,
                              void* d_out, int out_size, void* d_ws, size_t ws_size,
                              hipStream_t stream) {
    const float* enc = (const float*)d_in[0];   // [1024, 64, 512] fp32
    const float* W   = (const float*)d_in[1];   // [512, 512] fp32
    float* out       = (float*)d_out;           // [1024, 512] fp32
    _Float16* Wp     = (_Float16*)d_ws;         // 512 KB, B-fragment order
    (void)in_sizes; (void)n_in; (void)ws_size; (void)out_size;

    cast_w_kernel<<<128, 256, 0, stream>>>(W, Wp);
    routing_kernel<<<1024, NT, 0, stream>>>(enc, Wp, out);
}